// Round 8
// baseline (69.499 us; speedup 1.0000x reference)
//
#include <hip/hip_runtime.h>
#include <hip/hip_bf16.h>
#include <math.h>

// Problem constants: T=4096, B=64, D=64, SCALE = 1/8.
#define T_DIM 4096
#define B_DIM 64
#define NROWS (T_DIM * B_DIM)   // 262144 rows (r = t*64+b), 64 floats each
#define NTILES (NROWS / 16)     // 16384 16-row MFMA tiles; 4 tiles per wave

// Workspace layout (float offsets)
#define WS_MFRAG 0        // 4096 u16 (2048 f): M fragment-linear bf16
#define WS_VFRAG 2048     // 4096 u16: Wv fragment-linear bf16
#define WS_U     4096     // 64 f32: u[k] = sum_o bq[o]*Wk[o,k]
#define WS_W     4160     // 64 f32: w[d] = sum_o Wq[o,d]*bk[o]
#define WS_C     4224     // 1 f32:  c = bq.bk
#define WS_MX    4240     // 64 f32: per-b max
#define WS_INV   4304     // 64 f32: per-b 1/sum
#define WS_PM    4368     // 64x64 f32: partial max  [ck*64+b]
#define WS_PS    8464     // 64x64 f32: partial sum
#define WS_SCORE 16384    // [NROWS] scores, natural r order

typedef __attribute__((ext_vector_type(4))) float f32x4;
typedef __attribute__((ext_vector_type(8))) short bf16x8;

static __device__ inline short f2bf(float x) {
  __hip_bfloat16 h = __float2bfloat16(x);
  return *reinterpret_cast<short*>(&h);
}

static __device__ inline bf16x8 cvt8(const float4 a, const float4 b) {
  bf16x8 r;
  r[0] = f2bf(a.x); r[1] = f2bf(a.y); r[2] = f2bf(a.z); r[3] = f2bf(a.w);
  r[4] = f2bf(b.x); r[5] = f2bf(b.y); r[6] = f2bf(b.z); r[7] = f2bf(b.w);
  return r;
}

static __device__ inline float dot4(const float4 a, const float4 b, float acc) {
  acc = fmaf(a.x, b.x, acc); acc = fmaf(a.y, b.y, acc);
  acc = fmaf(a.z, b.z, acc); acc = fmaf(a.w, b.w, acc);
  return acc;
}

// Fragment-linear index (u16 units) for weight element W[d][k].
static __device__ __host__ inline int frag_idx(int d, int k) {
  return ((d >> 4) * 2 + (k >> 5)) * 512 +
         ((((k >> 3) & 3) * 16 + (d & 15)) * 8) + (k & 7);
}

// ---------------------------------------------------------------------------
// K1: bilinear constants; M and Wv stored bf16 fragment-linear; u,w,c f32.
__global__ __launch_bounds__(64) void k1_precompute(
    const float* __restrict__ Wq, const float* __restrict__ bq,
    const float* __restrict__ Wk, const float* __restrict__ bk,
    const float* __restrict__ Wv, float* __restrict__ ws) {
  const int tid = threadIdx.x;
  const int blk = blockIdx.x;
  unsigned short* __restrict__ mfrag = (unsigned short*)(ws + WS_MFRAG);
  unsigned short* __restrict__ vfrag = (unsigned short*)(ws + WS_VFRAG);
  if (blk < 64) {
    const int d = blk;
    float acc = 0.f;
#pragma unroll
    for (int o = 0; o < 64; ++o)
      acc = fmaf(Wq[o * 64 + d], Wk[o * 64 + tid], acc);
    const int idx = frag_idx(d, tid);
    mfrag[idx] = (unsigned short)f2bf(acc);
    vfrag[idx] = (unsigned short)f2bf(Wv[d * 64 + tid]);
  } else {
    float uacc = 0.f, wacc = 0.f, cacc = 0.f;
#pragma unroll
    for (int o = 0; o < 64; ++o) {
      uacc = fmaf(bq[o], Wk[o * 64 + tid], uacc);
      wacc = fmaf(Wq[o * 64 + tid], bk[o], wacc);
      cacc = fmaf(bq[o], bk[o], cacc);
    }
    ws[WS_U + tid] = uacc;
    ws[WS_W + tid] = wacc;
    if (tid == 0) ws[WS_C] = cacc;
  }
}

// ---------------------------------------------------------------------------
// K2: score[r] = 0.125*(e^T M f + w.e + u.f + c).
// 4 tiles/wave, register double-buffered pipeline: loads for tile i+1 stay
// in flight while tile i computes. Weights loaded once per wave.

#define K2_LOAD(Fj, Ej, t)                                                   \
  {                                                                          \
    const float* Fb_ = fnirs + (size_t)(t) * 1024;                           \
    const float* Eb_ = eeg + (size_t)(t) * 1024;                             \
    _Pragma("unroll") for (int j = 0; j < 4; ++j)                            \
        Fj[j] = *reinterpret_cast<const float4*>(Fb_ + j * 256 + lane * 4);  \
    _Pragma("unroll") for (int j = 0; j < 4; ++j)                            \
        Ej[j] = *reinterpret_cast<const float4*>(Eb_ + j * 256 + lane * 4);  \
  }

#define K2_COMP(Fj, Ej, t)                                                   \
  {                                                                          \
    const int rbase_ = (t) * 16;                                             \
    float uf_[4];                                                            \
    _Pragma("unroll") for (int j = 0; j < 4; ++j)                            \
        uf_[j] = dot4(Fj[j], u4, 0.f);                                       \
    _Pragma("unroll") for (int j = 0; j < 4; ++j) {                          \
      const int r_ = j * 4 + g;                                              \
      const int a_ = r_ * 64 + ((((c >> 1) ^ (r_ & 7)) << 3) + ((c & 1) << 2)); \
      *reinterpret_cast<float4*>(&L[a_]) = Fj[j];                            \
    }                                                                        \
    const int fr0_ = c * 64 + (((g) ^ (c & 7)) << 3);                        \
    const int fr1_ = c * 64 + (((4 + g) ^ (c & 7)) << 3);                    \
    const float4 p00_ = *reinterpret_cast<const float4*>(&L[fr0_]);          \
    const float4 p01_ = *reinterpret_cast<const float4*>(&L[fr0_ + 4]);      \
    const float4 p10_ = *reinterpret_cast<const float4*>(&L[fr1_]);          \
    const float4 p11_ = *reinterpret_cast<const float4*>(&L[fr1_ + 4]);      \
    const bf16x8 a0_ = cvt8(p00_, p01_);                                     \
    const bf16x8 a1_ = cvt8(p10_, p11_);                                     \
    f32x4 acc_[4];                                                           \
    _Pragma("unroll") for (int dt = 0; dt < 4; ++dt) {                       \
      acc_[dt] = __builtin_amdgcn_mfma_f32_16x16x32_bf16(bm[dt][0], a0_, zero, 0, 0, 0); \
      acc_[dt] = __builtin_amdgcn_mfma_f32_16x16x32_bf16(bm[dt][1], a1_, acc_[dt], 0, 0, 0); \
    }                                                                        \
    _Pragma("unroll") for (int dt = 0; dt < 4; ++dt) {                       \
      float4 hp_;                                                            \
      hp_.x = acc_[dt][0] + wf[dt].x; hp_.y = acc_[dt][1] + wf[dt].y;        \
      hp_.z = acc_[dt][2] + wf[dt].z; hp_.w = acc_[dt][3] + wf[dt].w;        \
      const int ch_ = dt * 2 + (g >> 1);                                     \
      const int a_ = c * 64 + (((ch_ ^ (c & 7)) << 3) + ((g & 1) << 2));     \
      *reinterpret_cast<float4*>(&L[a_]) = hp_;                              \
    }                                                                        \
    _Pragma("unroll") for (int j = 0; j < 4; ++j) {                          \
      const int r_ = j * 4 + g;                                              \
      const int a_ = r_ * 64 + ((((c >> 1) ^ (r_ & 7)) << 3) + ((c & 1) << 2)); \
      const float4 hp_ = *reinterpret_cast<const float4*>(&L[a_]);           \
      float p_ = dot4(Ej[j], hp_, uf_[j]);                                   \
      p_ += __shfl_xor(p_, 1, 64);                                           \
      p_ += __shfl_xor(p_, 2, 64);                                           \
      p_ += __shfl_xor(p_, 4, 64);                                           \
      p_ += __shfl_xor(p_, 8, 64);                                           \
      if (c == 0) score[rbase_ + j * 4 + g] = (p_ + cb) * 0.125f;            \
    }                                                                        \
  }

__global__ __launch_bounds__(256, 2) void k2_score_mfma(
    const float* __restrict__ eeg, const float* __restrict__ fnirs,
    const unsigned short* __restrict__ mfrag, const float* __restrict__ wvec,
    const float* __restrict__ uvec, const float* __restrict__ cvec,
    float* __restrict__ score) {
  __shared__ float lds[4][1024];
  const int tid = threadIdx.x;
  const int lane = tid & 63;
  const int wv = tid >> 6;
  const int wid = blockIdx.x * 4 + wv;
  const int c = lane & 15;
  const int g = lane >> 4;
  float* L = lds[wv];
  const f32x4 zero = {0.f, 0.f, 0.f, 0.f};

  // persistent per-wave weights
  bf16x8 bm[4][2];
#pragma unroll
  for (int dt = 0; dt < 4; ++dt)
#pragma unroll
    for (int kf = 0; kf < 2; ++kf)
      bm[dt][kf] = *reinterpret_cast<const bf16x8*>(
          mfrag + (((dt * 2 + kf) << 9) + lane * 8));
  float4 wf[4];
#pragma unroll
  for (int dt = 0; dt < 4; ++dt)
    wf[dt] = *reinterpret_cast<const float4*>(wvec + dt * 16 + g * 4);
  const float4 u4 = *reinterpret_cast<const float4*>(uvec + c * 4);
  const float cb = cvec[0];

  const int t0 = wid * 4;   // 4 contiguous tiles per wave
  float4 FA[4], EA[4], FB[4], EB[4];
  K2_LOAD(FA, EA, t0);
  K2_LOAD(FB, EB, t0 + 1);
  K2_COMP(FA, EA, t0);
  K2_LOAD(FA, EA, t0 + 2);
  K2_COMP(FB, EB, t0 + 1);
  K2_LOAD(FB, EB, t0 + 3);
  K2_COMP(FA, EA, t0 + 2);
  K2_COMP(FB, EB, t0 + 3);
}

// ---------------------------------------------------------------------------
// K3a: per-(64-t-chunk) online (m,s) for ALL b. lane = b -> coalesced reads.
__global__ __launch_bounds__(256) void k3a_partial(
    const float* __restrict__ sc, float* __restrict__ pm,
    float* __restrict__ ps) {
  __shared__ float sm[4][64], ss[4][64];
  const int tid = threadIdx.x;
  const int b = tid & 63;
  const int tq = tid >> 6;
  const int t0 = blockIdx.x * 64;
  float m = -1e30f, s = 0.f;
#pragma unroll
  for (int k = 0; k < 16; ++k) {
    const float v = sc[(size_t)(t0 + k * 4 + tq) * 64 + b];
    const float mn = fmaxf(m, v);
    s = s * __expf(m - mn) + __expf(v - mn);
    m = mn;
  }
  sm[tq][b] = m; ss[tq][b] = s;
  __syncthreads();
  if (tid < 64) {
    float M = sm[0][b], S = ss[0][b];
#pragma unroll
    for (int w = 1; w < 4; ++w) {
      const float m2 = sm[w][b], s2 = ss[w][b];
      const float Mn = fmaxf(M, m2);
      S = S * __expf(M - Mn) + s2 * __expf(m2 - Mn);
      M = Mn;
    }
    pm[blockIdx.x * 64 + b] = M;
    ps[blockIdx.x * 64 + b] = S;
  }
}

// K3b: combine 64 chunk-partials per b. One block.
__global__ __launch_bounds__(64) void k3b_combine(
    const float* __restrict__ pm, const float* __restrict__ ps,
    float* __restrict__ mx, float* __restrict__ inv) {
  const int b = threadIdx.x;
  float M = pm[b], S = ps[b];
#pragma unroll
  for (int ck = 1; ck < 64; ++ck) {
    const float m2 = pm[ck * 64 + b], s2 = ps[ck * 64 + b];
    const float Mn = fmaxf(M, m2);
    S = S * __expf(M - Mn) + s2 * __expf(m2 - Mn);
    M = Mn;
  }
  mx[b] = M;
  inv[b] = 1.0f / S;
}

// ---------------------------------------------------------------------------
// K4: out = eeg + attn*(Wv f + bv). Same 4-tile double-buffered pipeline.

#define K4_LOAD(Fj, Ej, scr, mxv, invv, t)                                   \
  {                                                                          \
    const float* Fb_ = fnirs + (size_t)(t) * 1024;                           \
    const float* Eb_ = eeg + (size_t)(t) * 1024;                             \
    _Pragma("unroll") for (int j = 0; j < 4; ++j)                            \
        Fj[j] = *reinterpret_cast<const float4*>(Fb_ + j * 256 + lane * 4);  \
    _Pragma("unroll") for (int j = 0; j < 4; ++j)                            \
        Ej[j] = *reinterpret_cast<const float4*>(Eb_ + j * 256 + lane * 4);  \
    scr = score[(t) * 16 + c];                                               \
    const int b_ = ((t) * 16 + c) & 63;                                      \
    mxv = mx[b_];                                                            \
    invv = inv[b_];                                                          \
  }

#define K4_COMP(Fj, Ej, scr, mxv, invv, t)                                   \
  {                                                                          \
    const int rbase_ = (t) * 16;                                             \
    _Pragma("unroll") for (int j = 0; j < 4; ++j) {                          \
      const int r_ = j * 4 + g;                                              \
      const int a_ = r_ * 64 + ((((c >> 1) ^ (r_ & 7)) << 3) + ((c & 1) << 2)); \
      *reinterpret_cast<float4*>(&L[a_]) = Fj[j];                            \
    }                                                                        \
    const int fr0_ = c * 64 + (((g) ^ (c & 7)) << 3);                        \
    const int fr1_ = c * 64 + (((4 + g) ^ (c & 7)) << 3);                    \
    const float4 p00_ = *reinterpret_cast<const float4*>(&L[fr0_]);          \
    const float4 p01_ = *reinterpret_cast<const float4*>(&L[fr0_ + 4]);      \
    const float4 p10_ = *reinterpret_cast<const float4*>(&L[fr1_]);          \
    const float4 p11_ = *reinterpret_cast<const float4*>(&L[fr1_ + 4]);      \
    const bf16x8 a0_ = cvt8(p00_, p01_);                                     \
    const bf16x8 a1_ = cvt8(p10_, p11_);                                     \
    f32x4 acc_[4];                                                           \
    _Pragma("unroll") for (int dt = 0; dt < 4; ++dt) {                       \
      acc_[dt] = __builtin_amdgcn_mfma_f32_16x16x32_bf16(bm[dt][0], a0_, zero, 0, 0, 0); \
      acc_[dt] = __builtin_amdgcn_mfma_f32_16x16x32_bf16(bm[dt][1], a1_, acc_[dt], 0, 0, 0); \
    }                                                                        \
    const float aC_ = __expf(scr - mxv) * invv;                              \
    _Pragma("unroll") for (int dt = 0; dt < 4; ++dt) {                       \
      float4 v4_;                                                            \
      v4_.x = aC_ * (acc_[dt][0] + bvf[dt].x);                               \
      v4_.y = aC_ * (acc_[dt][1] + bvf[dt].y);                               \
      v4_.z = aC_ * (acc_[dt][2] + bvf[dt].z);                               \
      v4_.w = aC_ * (acc_[dt][3] + bvf[dt].w);                               \
      const int ch_ = dt * 2 + (g >> 1);                                     \
      const int a_ = c * 64 + (((ch_ ^ (c & 7)) << 3) + ((g & 1) << 2));     \
      *reinterpret_cast<float4*>(&L[a_]) = v4_;                              \
    }                                                                        \
    float* Ob_ = out + (size_t)rbase_ * 64;                                  \
    _Pragma("unroll") for (int j = 0; j < 4; ++j) {                          \
      const int r_ = j * 4 + g;                                              \
      const int a_ = r_ * 64 + ((((c >> 1) ^ (r_ & 7)) << 3) + ((c & 1) << 2)); \
      const float4 v_ = *reinterpret_cast<const float4*>(&L[a_]);            \
      float4 o_;                                                             \
      o_.x = Ej[j].x + v_.x; o_.y = Ej[j].y + v_.y;                          \
      o_.z = Ej[j].z + v_.z; o_.w = Ej[j].w + v_.w;                          \
      *reinterpret_cast<float4*>(Ob_ + j * 256 + lane * 4) = o_;             \
    }                                                                        \
  }

__global__ __launch_bounds__(256, 2) void k4_output_mfma(
    const float* __restrict__ eeg, const float* __restrict__ fnirs,
    const unsigned short* __restrict__ vfrag, const float* __restrict__ bv,
    const float* __restrict__ score, const float* __restrict__ mx,
    const float* __restrict__ inv, float* __restrict__ out) {
  __shared__ float lds[4][1024];
  const int tid = threadIdx.x;
  const int lane = tid & 63;
  const int wv = tid >> 6;
  const int wid = blockIdx.x * 4 + wv;
  const int c = lane & 15;
  const int g = lane >> 4;
  float* L = lds[wv];
  const f32x4 zero = {0.f, 0.f, 0.f, 0.f};

  bf16x8 bm[4][2];
#pragma unroll
  for (int dt = 0; dt < 4; ++dt)
#pragma unroll
    for (int kf = 0; kf < 2; ++kf)
      bm[dt][kf] = *reinterpret_cast<const bf16x8*>(
          vfrag + (((dt * 2 + kf) << 9) + lane * 8));
  float4 bvf[4];
#pragma unroll
  for (int dt = 0; dt < 4; ++dt)
    bvf[dt] = *reinterpret_cast<const float4*>(bv + dt * 16 + g * 4);

  const int t0 = wid * 4;
  float4 FA[4], EA[4], FB[4], EB[4];
  float sA, mA, iA, sB, mB, iB;
  K4_LOAD(FA, EA, sA, mA, iA, t0);
  K4_LOAD(FB, EB, sB, mB, iB, t0 + 1);
  K4_COMP(FA, EA, sA, mA, iA, t0);
  K4_LOAD(FA, EA, sA, mA, iA, t0 + 2);
  K4_COMP(FB, EB, sB, mB, iB, t0 + 1);
  K4_LOAD(FB, EB, sB, mB, iB, t0 + 3);
  K4_COMP(FA, EA, sA, mA, iA, t0 + 2);
  K4_COMP(FB, EB, sB, mB, iB, t0 + 3);
}

// ---------------------------------------------------------------------------
extern "C" void kernel_launch(void* const* d_in, const int* in_sizes, int n_in,
                              void* d_out, int out_size, void* d_ws, size_t ws_size,
                              hipStream_t stream) {
  const float* eeg   = (const float*)d_in[0];
  const float* fnirs = (const float*)d_in[1];
  const float* Wq    = (const float*)d_in[2];
  const float* bq    = (const float*)d_in[3];
  const float* Wk    = (const float*)d_in[4];
  const float* bk    = (const float*)d_in[5];
  const float* Wv    = (const float*)d_in[6];
  const float* bv    = (const float*)d_in[7];
  float* out = (float*)d_out;
  float* ws  = (float*)d_ws;

  k1_precompute<<<65, 64, 0, stream>>>(Wq, bq, Wk, bk, Wv, ws);
  k2_score_mfma<<<NTILES / 16, 256, 0, stream>>>(
      eeg, fnirs, (const unsigned short*)(ws + WS_MFRAG), ws + WS_W,
      ws + WS_U, ws + WS_C, ws + WS_SCORE);
  k3a_partial<<<64, 256, 0, stream>>>(ws + WS_SCORE, ws + WS_PM, ws + WS_PS);
  k3b_combine<<<1, 64, 0, stream>>>(ws + WS_PM, ws + WS_PS,
                                    ws + WS_MX, ws + WS_INV);
  k4_output_mfma<<<NTILES / 16, 256, 0, stream>>>(
      eeg, fnirs, (const unsigned short*)(ws + WS_VFRAG), bv,
      ws + WS_SCORE, ws + WS_MX, ws + WS_INV, out);
}